// Round 3
// baseline (2630.114 us; speedup 1.0000x reference)
//
#include <hip/hip_runtime.h>
#include <math.h>
#include <stdint.h>
#include <stddef.h>

#define AS1 __attribute__((address_space(1)))
#define AS3 __attribute__((address_space(3)))

typedef __attribute__((ext_vector_type(8))) __bf16 bf16x8;
typedef __attribute__((ext_vector_type(4))) float f32x4;

// Problem constants
#define SQ   256
#define BQ   32
#define EQ   300
#define HQ   2400
#define MQ   (SQ * BQ)      // 8192 rows
#define N3H  7200           // 3 gates
#define N2H  4800           // Z,F only (layer 3)
#define KP1  320            // padded E  (mult of 64)
#define KP2  2432           // padded H  (mult of 64)

// ---------- helpers ----------
__device__ __forceinline__ uint16_t f2bf(float x) {
    uint32_t u = __float_as_uint(x);
    u += 0x7FFFu + ((u >> 16) & 1u);
    return (uint16_t)(u >> 16);
}
__device__ __forceinline__ float bf2f(uint16_t b) {
    return __uint_as_float(((uint32_t)b) << 16);
}
__device__ __forceinline__ float sigm(float x) { return 1.f / (1.f + __expf(-x)); }
__device__ __forceinline__ float tanh_f(float x) { return 2.f / (1.f + __expf(-2.f * x)) - 1.f; }

// ---------- fp32 -> (bf16 hi, bf16 lo) with zero K-padding (pairwise) ----------
__global__ void conv_split(const float* __restrict__ src, uint16_t* __restrict__ hi,
                           uint16_t* __restrict__ lo, int rows, int K, int Kp) {
    int idx = blockIdx.x * 256 + threadIdx.x;     // pair index
    int kp2 = Kp >> 1;
    if (idx >= rows * kp2) return;
    int r = idx / kp2;
    int k = (idx - r * kp2) << 1;
    float2 v = make_float2(0.f, 0.f);
    if (k < K) v = *(const float2*)(src + (size_t)r * K + k);
    uint16_t h0 = f2bf(v.x), h1 = f2bf(v.y);
    uint32_t hw = (uint32_t)h0 | ((uint32_t)h1 << 16);
    uint32_t lw = (uint32_t)f2bf(v.x - bf2f(h0)) | ((uint32_t)f2bf(v.y - bf2f(h1)) << 16);
    size_t o = (size_t)r * Kp + k;
    *(uint32_t*)(hi + o) = hw;
    *(uint32_t*)(lo + o) = lw;
}

// zero the pad columns [HQ, KP2) of the X (hidden) split buffers, once per call
__global__ void zero_pad_X(uint16_t* __restrict__ hi, uint16_t* __restrict__ lo) {
    int idx = blockIdx.x * 256 + threadIdx.x;
    if (idx >= MQ * ((KP2 - HQ) >> 1)) return;
    int r = idx >> 4;                 // 16 pad pairs
    int c = (idx & 15) << 1;
    size_t off = (size_t)r * KP2 + HQ + c;
    *(uint32_t*)(hi + off) = 0u;
    *(uint32_t*)(lo + off) = 0u;
}

// ---------- segmented-K split GEMM, 256x256 tile, 8 waves, slab-ring pipeline ----------
// Logical K'' = 3*KP: seg0 = Ahi*Whi, seg1 = Ahi*Wlo, seg2 = Alo*Whi (fp32 accumulate).
// LDS: 4 slabs x (A[256][32] + B[256][32]) bf16 = 4 x 32KiB = 128 KiB.
// Pipeline: stage slab j+3 while computing slab j; vmcnt(12) = 3 slabs in flight.
// T2 swizzle: LDS byte col ^= (row&3)<<4 on the read side; inverse baked into the
// global source address (linear global_load_lds destination).
template<int KP>
__global__ __launch_bounds__(512, 2) void gemm256(
    const uint16_t* __restrict__ Ahi, const uint16_t* __restrict__ Alo,
    const uint16_t* __restrict__ Whi, const uint16_t* __restrict__ Wlo,
    float* __restrict__ Y, int Ncols, int rowbase)
{
    constexpr int SPS   = KP / 32;   // slabs per segment
    constexpr int NSLAB = 3 * SPS;
    extern __shared__ char smem[];   // 131072 bytes

    const int tid  = threadIdx.x;
    const int lane = tid & 63;
    const int wave = tid >> 6;
    const int wm   = wave >> 2;          // 0..1
    const int wn   = wave & 3;           // 0..3
    const int lrow0 = blockIdx.y << 8;   // chunk-local row base
    const int col0  = blockIdx.x << 8;
    const int arow0 = rowbase + lrow0;   // absolute A row base

    // ---- staging constants (per thread) ----
    const int tq    = tid >> 2;                                   // 0..127 row in half
    const int c_log = (((tid & 3) << 4) ^ ((tq & 3) << 4));       // pre-swizzled src byte col
    const int k_el  = c_log >> 1;                                 // element offset 0/8/16/24
    const size_t aofs0 = (size_t)(arow0 + tq) * KP + k_el;
    const size_t aofs1 = (size_t)(arow0 + 128 + tq) * KP + k_el;
    const int wr0 = min(col0 + tq, Ncols - 1);
    const int wr1 = min(col0 + 128 + tq, Ncols - 1);
    const size_t bofs0 = (size_t)wr0 * KP + k_el;
    const size_t bofs1 = (size_t)wr1 * KP + k_el;
    const int ldst = tid << 4;                                    // linear LDS dest byte

    // ---- compute constants ----
    const int cphys = (((lane >> 4) << 4) ^ ((lane & 3) << 4));   // swizzled read col
    const int abase = (((wm << 7) + (lane & 15)) << 6) + cphys;
    const int bbase = (((wn << 6) + (lane & 15)) << 6) + cphys;

    f32x4 acc[8][4];
    {
        f32x4 z = {0.f, 0.f, 0.f, 0.f};
#pragma unroll
        for (int mb = 0; mb < 8; ++mb)
#pragma unroll
            for (int nb = 0; nb < 4; ++nb) acc[mb][nb] = z;
    }

    int sseg = 0, sk0 = 0;   // next slab to stage
    auto stage = [&](int slot) {
        const uint16_t* Ab = (sseg == 2) ? Alo : Ahi;
        const uint16_t* Bb = (sseg == 1) ? Wlo : Whi;
        char* dst = smem + (slot << 15);
        __builtin_amdgcn_global_load_lds((const AS1 uint32_t*)(Ab + aofs0 + sk0),
                                         (AS3 uint32_t*)(dst + ldst),          16, 0, 0);
        __builtin_amdgcn_global_load_lds((const AS1 uint32_t*)(Ab + aofs1 + sk0),
                                         (AS3 uint32_t*)(dst + 8192  + ldst),  16, 0, 0);
        __builtin_amdgcn_global_load_lds((const AS1 uint32_t*)(Bb + bofs0 + sk0),
                                         (AS3 uint32_t*)(dst + 16384 + ldst),  16, 0, 0);
        __builtin_amdgcn_global_load_lds((const AS1 uint32_t*)(Bb + bofs1 + sk0),
                                         (AS3 uint32_t*)(dst + 24576 + ldst),  16, 0, 0);
        sk0 += 32;
        if (sk0 == KP) { sk0 = 0; ++sseg; }
    };

    auto compute = [&](int slot) {
        const char* sa = smem + (slot << 15);
        const char* sb = sa + 16384;
        bf16x8 af[8], bfr[4];
#pragma unroll
        for (int mb = 0; mb < 8; ++mb) af[mb] = *(const bf16x8*)(sa + abase + (mb << 10));
#pragma unroll
        for (int nb = 0; nb < 4; ++nb) bfr[nb] = *(const bf16x8*)(sb + bbase + (nb << 10));
        __builtin_amdgcn_s_setprio(1);
#pragma unroll
        for (int mb = 0; mb < 8; ++mb)
#pragma unroll
            for (int nb = 0; nb < 4; ++nb)
                acc[mb][nb] = __builtin_amdgcn_mfma_f32_16x16x32_bf16(af[mb], bfr[nb], acc[mb][nb], 0, 0, 0);
        __builtin_amdgcn_s_setprio(0);
    };

    // prologue: 3 slabs in flight
    stage(0); stage(1); stage(2);

    for (int j = 0; j < NSLAB - 3; ++j) {
        stage((j + 3) & 3);
        asm volatile("s_waitcnt vmcnt(12)" ::: "memory");  // slab j landed (own loads)
        asm volatile("s_barrier" ::: "memory");            // everyone's slab-j loads landed
        compute(j & 3);
        asm volatile("s_barrier" ::: "memory");            // reads done before slot reuse
    }
    // tail: no more staging; drain counted
    asm volatile("s_waitcnt vmcnt(8)" ::: "memory");
    asm volatile("s_barrier" ::: "memory");
    compute((NSLAB - 3) & 3);
    asm volatile("s_waitcnt vmcnt(4)" ::: "memory");
    asm volatile("s_barrier" ::: "memory");
    compute((NSLAB - 2) & 3);
    asm volatile("s_waitcnt vmcnt(0)" ::: "memory");
    asm volatile("s_barrier" ::: "memory");
    compute((NSLAB - 1) & 3);

    // epilogue: D col = lane&15, row = (lane>>4)*4 + r   (chunk-local Y rows)
    const int orow = (lane >> 4) << 2;
    const int ocol = lane & 15;
#pragma unroll
    for (int mb = 0; mb < 8; ++mb) {
        const int r0 = lrow0 + (wm << 7) + (mb << 4) + orow;
#pragma unroll
        for (int nb = 0; nb < 4; ++nb) {
            const int c = col0 + (wn << 6) + (nb << 4) + ocol;
            if (c < Ncols) {
                float* yp = Y + (size_t)r0 * Ncols + c;
#pragma unroll
                for (int r = 0; r < 4; ++r) yp[(size_t)r * Ncols] = acc[mb][nb][r];
            }
        }
    }
}

// ---------- fo-pool scan chunk [s0, s0+Sc); 2 h-columns per thread ----------
// MODE 0: layer1 (finals=c), MODE 1: layer2 (finals+=c), MODE 2: layer3 (Z,F only; output)
template<int MODE>
__global__ void scan_k(const float* __restrict__ Y, const float* __restrict__ bias,
                       uint16_t* __restrict__ hhi, uint16_t* __restrict__ hlo,
                       float* __restrict__ cst, float* __restrict__ fin,
                       float* __restrict__ out, const int* __restrict__ slen,
                       int s0, int Sc)
{
    int idx = blockIdx.x * 256 + threadIdx.x;     // pair index
    if (idx >= BQ * (HQ >> 1)) return;
    int b = idx / (HQ >> 1);
    int h = (idx - b * (HQ >> 1)) << 1;
    const int Ncols = (MODE == 2) ? N2H : N3H;

    const float2 bz = *(const float2*)(bias + h);
    const float2 bg = *(const float2*)(bias + HQ + h);
    const float2 bo = (MODE == 2) ? make_float2(0.f, 0.f) : *(const float2*)(bias + 2 * HQ + h);
    float2 c = (s0 == 0) ? make_float2(0.f, 0.f) : *(const float2*)(cst + b * HQ + h);

    const float* yp = Y + (size_t)b * Ncols + h;
    for (int si = 0; si < Sc; ++si) {
        const float* row = yp + (size_t)si * (BQ * Ncols);
        float2 zr = *(const float2*)(row);
        float2 fr = *(const float2*)(row + HQ);
        float z0 = tanh_f(zr.x + bz.x), z1 = tanh_f(zr.y + bz.y);
        float f0 = sigm(fr.x + bg.x),   f1 = sigm(fr.y + bg.y);
        c.x = f0 * c.x + (1.f - f0) * z0;
        c.y = f1 * c.y + (1.f - f1) * z1;
        if (MODE != 2) {
            float2 orv = *(const float2*)(row + 2 * HQ);
            float o0 = sigm(orv.x + bo.x), o1 = sigm(orv.y + bo.y);
            float h0 = o0 * c.x, h1 = o1 * c.y;
            uint16_t hb0 = f2bf(h0), hb1 = f2bf(h1);
            size_t off = ((size_t)(s0 + si) * BQ + b) * KP2 + h;
            *(uint32_t*)(hhi + off) = (uint32_t)hb0 | ((uint32_t)hb1 << 16);
            *(uint32_t*)(hlo + off) =
                (uint32_t)f2bf(h0 - bf2f(hb0)) | ((uint32_t)f2bf(h1 - bf2f(hb1)) << 16);
        }
    }
    if (s0 + Sc < SQ) {
        *(float2*)(cst + b * HQ + h) = c;
    } else {
        if (MODE == 0) {
            *(float2*)(fin + b * HQ + h) = c;
        } else if (MODE == 1) {
            float2 t = *(const float2*)(fin + b * HQ + h);
            t.x += c.x; t.y += c.y;
            *(float2*)(fin + b * HQ + h) = t;
        } else {
            float inv = 1.f / (float)slen[b];
            float2 t = *(const float2*)(fin + b * HQ + h);
            out[b * HQ + h]     = (t.x + c.x) * inv;
            out[b * HQ + h + 1] = (t.y + c.y) * inv;
        }
    }
}

extern "C" void kernel_launch(void* const* d_in, const int* in_sizes, int n_in,
                              void* d_out, int out_size, void* d_ws, size_t ws_size,
                              hipStream_t stream) {
    const float* sent = (const float*)d_in[0];
    const int*   slen = (const int*)d_in[1];
    const float* Wl[3] = {(const float*)d_in[2], (const float*)d_in[4], (const float*)d_in[6]};
    const float* bl[3] = {(const float*)d_in[3], (const float*)d_in[5], (const float*)d_in[7]};
    float* out = (float*)d_out;

    // allow 128 KiB dynamic LDS for the GEMM kernels (host-side, capture-safe)
    (void)hipFuncSetAttribute((const void*)gemm256<KP1>,
                              hipFuncAttributeMaxDynamicSharedMemorySize, 131072);
    (void)hipFuncSetAttribute((const void*)gemm256<KP2>,
                              hipFuncAttributeMaxDynamicSharedMemorySize, 131072);

    // ws layout (fixed part ~153.4 MiB; Y chunk sized to fit ws_size)
    char* ws = (char*)d_ws;
    uint16_t* A1hi = (uint16_t*)ws;                    // [8192][320]
    uint16_t* A1lo = A1hi + (size_t)MQ * KP1;
    uint16_t* Xhi  = A1lo + (size_t)MQ * KP1;          // [8192][2432]
    uint16_t* Xlo  = Xhi  + (size_t)MQ * KP2;
    uint16_t* Whi  = Xlo  + (size_t)MQ * KP2;          // [7200][2432] max
    uint16_t* Wlo  = Whi  + (size_t)N3H * KP2;
    float*    cst  = (float*)(Wlo + (size_t)N3H * KP2);// [32][2400]
    float*    fin  = cst + (size_t)BQ * HQ;            // [32][2400]
    float*    Yc   = fin + (size_t)BQ * HQ;            // [Sc*32][7200] fp32

    const size_t fixed = (size_t)((char*)Yc - ws);
    int Sc = 8;
    const int sc_opts[6] = {256, 128, 64, 32, 16, 8};  // multiples of 8 (M-tile = 256 rows)
    for (int i = 0; i < 6; ++i) {
        size_t need = fixed + (size_t)sc_opts[i] * BQ * N3H * 4 + 256;
        if (need <= ws_size) { Sc = sc_opts[i]; break; }
    }

    conv_split<<<(MQ * (KP1 / 2) + 255) / 256, 256, 0, stream>>>(sent, A1hi, A1lo, MQ, EQ, KP1);
    zero_pad_X<<<(MQ * 16 + 255) / 256, 256, 0, stream>>>(Xhi, Xlo);

    const int sgrid = (BQ * (HQ / 2) + 255) / 256;
    for (int l = 0; l < 3; ++l) {
        const int Ncols = (l == 2) ? N2H : N3H;
        const int Kp    = (l == 0) ? KP1 : KP2;
        const int Ksrc  = (l == 0) ? EQ  : HQ;
        conv_split<<<(Ncols * (Kp / 2) + 255) / 256, 256, 0, stream>>>(Wl[l], Whi, Wlo, Ncols, Ksrc, Kp);
        const uint16_t* Ah = (l == 0) ? A1hi : Xhi;
        const uint16_t* Al = (l == 0) ? A1lo : Xlo;
        dim3 gg((Ncols + 255) / 256, Sc / 8);
        for (int s0 = 0; s0 < SQ; s0 += Sc) {
            if (l == 0)
                gemm256<KP1><<<gg, 512, 131072, stream>>>(Ah, Al, Whi, Wlo, Yc, Ncols, s0 * BQ);
            else
                gemm256<KP2><<<gg, 512, 131072, stream>>>(Ah, Al, Whi, Wlo, Yc, Ncols, s0 * BQ);
            if (l == 0)
                scan_k<0><<<sgrid, 256, 0, stream>>>(Yc, bl[0], Xhi, Xlo, cst, fin, nullptr, nullptr, s0, Sc);
            else if (l == 1)
                scan_k<1><<<sgrid, 256, 0, stream>>>(Yc, bl[1], Xhi, Xlo, cst, fin, nullptr, nullptr, s0, Sc);
            else
                scan_k<2><<<sgrid, 256, 0, stream>>>(Yc, bl[2], nullptr, nullptr, cst, fin, out, slen, s0, Sc);
        }
    }
}

// Round 4
// 2199.374 us; speedup vs baseline: 1.1958x; 1.1958x over previous
//
#include <hip/hip_runtime.h>
#include <math.h>
#include <stdint.h>
#include <stddef.h>

#define AS1 __attribute__((address_space(1)))
#define AS3 __attribute__((address_space(3)))

typedef __attribute__((ext_vector_type(8))) __bf16 bf16x8;
typedef __attribute__((ext_vector_type(4))) float f32x4;

// Problem constants
#define SQ   256
#define BQ   32
#define EQ   300
#define HQ   2400
#define MQ   (SQ * BQ)      // 8192 rows
#define N3H  7200           // 3 gates
#define N2H  4800           // Z,F only (layer 3)
#define KP1  320            // padded E  (mult of 64)
#define KP2  2432           // padded H  (mult of 64)

// ---------- helpers ----------
__device__ __forceinline__ uint16_t f2bf(float x) {
    uint32_t u = __float_as_uint(x);
    u += 0x7FFFu + ((u >> 16) & 1u);
    return (uint16_t)(u >> 16);
}
__device__ __forceinline__ float bf2f(uint16_t b) {
    return __uint_as_float(((uint32_t)b) << 16);
}
__device__ __forceinline__ float sigm(float x) { return 1.f / (1.f + __expf(-x)); }
__device__ __forceinline__ float tanh_f(float x) { return 2.f / (1.f + __expf(-2.f * x)) - 1.f; }

// ---------- fp32 -> (bf16 hi, bf16 lo) with zero K-padding (pairwise) ----------
__global__ void conv_split(const float* __restrict__ src, uint16_t* __restrict__ hi,
                           uint16_t* __restrict__ lo, int rows, int K, int Kp) {
    int idx = blockIdx.x * 256 + threadIdx.x;     // pair index
    int kp2 = Kp >> 1;
    if (idx >= rows * kp2) return;
    int r = idx / kp2;
    int k = (idx - r * kp2) << 1;
    float2 v = make_float2(0.f, 0.f);
    if (k < K) v = *(const float2*)(src + (size_t)r * K + k);
    uint16_t h0 = f2bf(v.x), h1 = f2bf(v.y);
    uint32_t hw = (uint32_t)h0 | ((uint32_t)h1 << 16);
    uint32_t lw = (uint32_t)f2bf(v.x - bf2f(h0)) | ((uint32_t)f2bf(v.y - bf2f(h1)) << 16);
    size_t o = (size_t)r * Kp + k;
    *(uint32_t*)(hi + o) = hw;
    *(uint32_t*)(lo + o) = lw;
}

// zero the pad columns [HQ, KP2) of the X (hidden) split buffers, once per call
__global__ void zero_pad_X(uint16_t* __restrict__ hi, uint16_t* __restrict__ lo) {
    int idx = blockIdx.x * 256 + threadIdx.x;
    if (idx >= MQ * ((KP2 - HQ) >> 1)) return;
    int r = idx >> 4;                 // 16 pad pairs
    int c = (idx & 15) << 1;
    size_t off = (size_t)r * KP2 + HQ + c;
    *(uint32_t*)(hi + off) = 0u;
    *(uint32_t*)(lo + off) = 0u;
}

// ---------- fused-segment split GEMM, 256x256 tile, 8 waves ----------
// Per K-step (32 wide): stage Ahi/Alo/Whi/Wlo slabs (64 KiB), compute
// acc += Ahi*Whi + Ahi*Wlo + Alo*Whi (96 MFMA/wave). Double-buffered (2 x 64 KiB).
// Counted vmcnt(8) keeps next slab's 8 loads in flight across the barrier.
// LDS swizzle: byte col chunk c_phys = c_log ^ ((row>>1)&3); inverse baked into the
// global source address (linear global_load_lds destination), applied on ds_read.
// XCD grouping: xcd = blockIdx.x & 7 owns cols == xcd (mod 8), rows fastest, so the
// nrb row-blocks sharing a B panel run in k-lockstep on one XCD's L2.
template<int KP>
__global__ __launch_bounds__(512, 2) void gemm256(
    const uint16_t* __restrict__ Ahi, const uint16_t* __restrict__ Alo,
    const uint16_t* __restrict__ Whi, const uint16_t* __restrict__ Wlo,
    float* __restrict__ Y, int Ncols, int rowbase, int nrb, int ncb)
{
    constexpr int NK = KP / 32;
    extern __shared__ char smem[];   // 131072 bytes

    const int d   = blockIdx.x;
    const int xcd = d & 7;
    const int rr  = d >> 3;
    const int row = rr % nrb;
    const int col = (rr / nrb) * 8 + xcd;
    if (col >= ncb) return;
    const int lrow0 = row << 8;          // chunk-local row base
    const int col0  = col << 8;
    const int arow0 = rowbase + lrow0;   // absolute A row base

    const int tid  = threadIdx.x;
    const int lane = tid & 63;
    const int wave = tid >> 6;
    const int wm   = wave >> 2;          // 0..1
    const int wn   = wave & 3;           // 0..3

    // ---- staging constants ----
    const int tq   = tid >> 2;                         // row 0..127 (half-tile)
    const int kc   = tid & 3;                          // dest 16B chunk
    const int kswz = ((kc ^ ((tq >> 1) & 3)) << 3);    // pre-swizzled src k-element
    const size_t aof0 = (size_t)(arow0 + tq) * KP + kswz;
    const size_t aof1 = aof0 + (size_t)128 * KP;
    const int w0 = min(col0 + tq, Ncols - 1);
    const int w1 = min(col0 + 128 + tq, Ncols - 1);
    const size_t bof0 = (size_t)w0 * KP + kswz;
    const size_t bof1 = (size_t)w1 * KP + kswz;
    const int ldst = tid << 4;                         // linear LDS dest byte

    // ---- compute constants ----
    const int fr    = lane & 15;
    const int q     = lane >> 4;
    const int cphys = ((q ^ ((fr >> 1) & 3)) << 4);    // swizzled read byte col
    const int abase = (((wm << 7) + fr) << 6) + cphys; // byte within a 16 KiB region
    const int bbase = (((wn << 6) + fr) << 6) + cphys;

    f32x4 acc[8][4];
    {
        f32x4 z = {0.f, 0.f, 0.f, 0.f};
#pragma unroll
        for (int mb = 0; mb < 8; ++mb)
#pragma unroll
            for (int nb = 0; nb < 4; ++nb) acc[mb][nb] = z;
    }

    auto stage = [&](int slot, int k0) {
        char* dst = smem + (slot << 16);
        __builtin_amdgcn_global_load_lds((const AS1 uint32_t*)(Ahi + aof0 + k0),
                                         (AS3 uint32_t*)(dst + ldst),                 16, 0, 0);
        __builtin_amdgcn_global_load_lds((const AS1 uint32_t*)(Ahi + aof1 + k0),
                                         (AS3 uint32_t*)(dst + 8192  + ldst),         16, 0, 0);
        __builtin_amdgcn_global_load_lds((const AS1 uint32_t*)(Alo + aof0 + k0),
                                         (AS3 uint32_t*)(dst + 16384 + ldst),         16, 0, 0);
        __builtin_amdgcn_global_load_lds((const AS1 uint32_t*)(Alo + aof1 + k0),
                                         (AS3 uint32_t*)(dst + 16384 + 8192 + ldst),  16, 0, 0);
        __builtin_amdgcn_global_load_lds((const AS1 uint32_t*)(Whi + bof0 + k0),
                                         (AS3 uint32_t*)(dst + 32768 + ldst),         16, 0, 0);
        __builtin_amdgcn_global_load_lds((const AS1 uint32_t*)(Whi + bof1 + k0),
                                         (AS3 uint32_t*)(dst + 32768 + 8192 + ldst),  16, 0, 0);
        __builtin_amdgcn_global_load_lds((const AS1 uint32_t*)(Wlo + bof0 + k0),
                                         (AS3 uint32_t*)(dst + 49152 + ldst),         16, 0, 0);
        __builtin_amdgcn_global_load_lds((const AS1 uint32_t*)(Wlo + bof1 + k0),
                                         (AS3 uint32_t*)(dst + 49152 + 8192 + ldst),  16, 0, 0);
    };

    auto compute = [&](int slot) {
        const char* sa  = smem + (slot << 16);
        const char* sal = sa + 16384;
        const char* sbh = sa + 32768;
        const char* sbl = sa + 49152;
        bf16x8 a[8], bh[4], bl[4];
#pragma unroll
        for (int mb = 0; mb < 8; ++mb) a[mb] = *(const bf16x8*)(sa + abase + (mb << 10));
#pragma unroll
        for (int nb = 0; nb < 4; ++nb) bh[nb] = *(const bf16x8*)(sbh + bbase + (nb << 10));
#pragma unroll
        for (int nb = 0; nb < 4; ++nb) bl[nb] = *(const bf16x8*)(sbl + bbase + (nb << 10));
        __builtin_amdgcn_s_setprio(1);
#pragma unroll
        for (int mb = 0; mb < 8; ++mb)
#pragma unroll
            for (int nb = 0; nb < 4; ++nb)
                acc[mb][nb] = __builtin_amdgcn_mfma_f32_16x16x32_bf16(a[mb], bh[nb], acc[mb][nb], 0, 0, 0);
#pragma unroll
        for (int mb = 0; mb < 8; ++mb)
#pragma unroll
            for (int nb = 0; nb < 4; ++nb)
                acc[mb][nb] = __builtin_amdgcn_mfma_f32_16x16x32_bf16(a[mb], bl[nb], acc[mb][nb], 0, 0, 0);
        __builtin_amdgcn_s_setprio(0);
#pragma unroll
        for (int mb = 0; mb < 8; ++mb) a[mb] = *(const bf16x8*)(sal + abase + (mb << 10));
        __builtin_amdgcn_s_setprio(1);
#pragma unroll
        for (int mb = 0; mb < 8; ++mb)
#pragma unroll
            for (int nb = 0; nb < 4; ++nb)
                acc[mb][nb] = __builtin_amdgcn_mfma_f32_16x16x32_bf16(a[mb], bh[nb], acc[mb][nb], 0, 0, 0);
        __builtin_amdgcn_s_setprio(0);
    };

    stage(0, 0);
    for (int j = 0; j < NK; ++j) {
        if (j + 1 < NK) {
            stage((j + 1) & 1, (j + 1) << 5);
            asm volatile("s_waitcnt vmcnt(8)" ::: "memory");   // slab j landed
        } else {
            asm volatile("s_waitcnt vmcnt(0)" ::: "memory");
        }
        asm volatile("s_barrier" ::: "memory");                // everyone's slab-j landed
        compute(j & 1);
        asm volatile("s_barrier" ::: "memory");                // reads done before restage
    }

    // epilogue: D col = lane&15, row = (lane>>4)*4 + r   (chunk-local Y rows)
    const int orow = (lane >> 4) << 2;
    const int ocol = lane & 15;
#pragma unroll
    for (int mb = 0; mb < 8; ++mb) {
        const int r0 = lrow0 + (wm << 7) + (mb << 4) + orow;
#pragma unroll
        for (int nb = 0; nb < 4; ++nb) {
            const int c = col0 + (wn << 6) + (nb << 4) + ocol;
            if (c < Ncols) {
                float* yp = Y + (size_t)r0 * Ncols + c;
#pragma unroll
                for (int r = 0; r < 4; ++r) yp[(size_t)r * Ncols] = acc[mb][nb][r];
            }
        }
    }
}

// ---------- fo-pool scan chunk [s0, s0+Sc); 2 h-columns per thread ----------
// MODE 0: layer1 (finals=c), MODE 1: layer2 (finals+=c), MODE 2: layer3 (Z,F only; output)
template<int MODE>
__global__ void scan_k(const float* __restrict__ Y, const float* __restrict__ bias,
                       uint16_t* __restrict__ hhi, uint16_t* __restrict__ hlo,
                       float* __restrict__ cst, float* __restrict__ fin,
                       float* __restrict__ out, const int* __restrict__ slen,
                       int s0, int Sc)
{
    int idx = blockIdx.x * 256 + threadIdx.x;     // pair index
    if (idx >= BQ * (HQ >> 1)) return;
    int b = idx / (HQ >> 1);
    int h = (idx - b * (HQ >> 1)) << 1;
    const int Ncols = (MODE == 2) ? N2H : N3H;

    const float2 bz = *(const float2*)(bias + h);
    const float2 bg = *(const float2*)(bias + HQ + h);
    const float2 bo = (MODE == 2) ? make_float2(0.f, 0.f) : *(const float2*)(bias + 2 * HQ + h);
    float2 c = (s0 == 0) ? make_float2(0.f, 0.f) : *(const float2*)(cst + b * HQ + h);

    const float* yp = Y + (size_t)b * Ncols + h;
    for (int si = 0; si < Sc; ++si) {
        const float* row = yp + (size_t)si * (BQ * Ncols);
        float2 zr = *(const float2*)(row);
        float2 fr = *(const float2*)(row + HQ);
        float z0 = tanh_f(zr.x + bz.x), z1 = tanh_f(zr.y + bz.y);
        float f0 = sigm(fr.x + bg.x),   f1 = sigm(fr.y + bg.y);
        c.x = f0 * c.x + (1.f - f0) * z0;
        c.y = f1 * c.y + (1.f - f1) * z1;
        if (MODE != 2) {
            float2 orv = *(const float2*)(row + 2 * HQ);
            float o0 = sigm(orv.x + bo.x), o1 = sigm(orv.y + bo.y);
            float h0 = o0 * c.x, h1 = o1 * c.y;
            uint16_t hb0 = f2bf(h0), hb1 = f2bf(h1);
            size_t off = ((size_t)(s0 + si) * BQ + b) * KP2 + h;
            *(uint32_t*)(hhi + off) = (uint32_t)hb0 | ((uint32_t)hb1 << 16);
            *(uint32_t*)(hlo + off) =
                (uint32_t)f2bf(h0 - bf2f(hb0)) | ((uint32_t)f2bf(h1 - bf2f(hb1)) << 16);
        }
    }
    if (s0 + Sc < SQ) {
        *(float2*)(cst + b * HQ + h) = c;
    } else {
        if (MODE == 0) {
            *(float2*)(fin + b * HQ + h) = c;
        } else if (MODE == 1) {
            float2 t = *(const float2*)(fin + b * HQ + h);
            t.x += c.x; t.y += c.y;
            *(float2*)(fin + b * HQ + h) = t;
        } else {
            float inv = 1.f / (float)slen[b];
            float2 t = *(const float2*)(fin + b * HQ + h);
            out[b * HQ + h]     = (t.x + c.x) * inv;
            out[b * HQ + h + 1] = (t.y + c.y) * inv;
        }
    }
}

extern "C" void kernel_launch(void* const* d_in, const int* in_sizes, int n_in,
                              void* d_out, int out_size, void* d_ws, size_t ws_size,
                              hipStream_t stream) {
    const float* sent = (const float*)d_in[0];
    const int*   slen = (const int*)d_in[1];
    const float* Wl[3] = {(const float*)d_in[2], (const float*)d_in[4], (const float*)d_in[6]};
    const float* bl[3] = {(const float*)d_in[3], (const float*)d_in[5], (const float*)d_in[7]};
    float* out = (float*)d_out;

    // allow 128 KiB dynamic LDS for the GEMM kernels (host-side, capture-safe)
    (void)hipFuncSetAttribute((const void*)gemm256<KP1>,
                              hipFuncAttributeMaxDynamicSharedMemorySize, 131072);
    (void)hipFuncSetAttribute((const void*)gemm256<KP2>,
                              hipFuncAttributeMaxDynamicSharedMemorySize, 131072);

    // ws layout (fixed part ~153.4 MiB; Y chunk sized to fit ws_size)
    char* ws = (char*)d_ws;
    uint16_t* A1hi = (uint16_t*)ws;                    // [8192][320]
    uint16_t* A1lo = A1hi + (size_t)MQ * KP1;
    uint16_t* Xhi  = A1lo + (size_t)MQ * KP1;          // [8192][2432]
    uint16_t* Xlo  = Xhi  + (size_t)MQ * KP2;
    uint16_t* Whi  = Xlo  + (size_t)MQ * KP2;          // [7200][2432] max
    uint16_t* Wlo  = Whi  + (size_t)N3H * KP2;
    float*    cst  = (float*)(Wlo + (size_t)N3H * KP2);// [32][2400]
    float*    fin  = cst + (size_t)BQ * HQ;            // [32][2400]
    float*    Yc   = fin + (size_t)BQ * HQ;            // [Sc*32][7200] fp32

    const size_t fixed = (size_t)((char*)Yc - ws);
    int Sc = 8;
    const int sc_opts[6] = {256, 128, 64, 32, 16, 8};  // multiples of 8 (M-tile = 256 rows)
    for (int i = 0; i < 6; ++i) {
        size_t need = fixed + (size_t)sc_opts[i] * BQ * N3H * 4 + 256;
        if (need <= ws_size) { Sc = sc_opts[i]; break; }
    }
    const int nrb = Sc / 8;   // 256-row tiles per chunk

    conv_split<<<(MQ * (KP1 / 2) + 255) / 256, 256, 0, stream>>>(sent, A1hi, A1lo, MQ, EQ, KP1);
    zero_pad_X<<<(MQ * 16 + 255) / 256, 256, 0, stream>>>(Xhi, Xlo);

    const int sgrid = (BQ * (HQ / 2) + 255) / 256;
    for (int l = 0; l < 3; ++l) {
        const int Ncols = (l == 2) ? N2H : N3H;
        const int Kp    = (l == 0) ? KP1 : KP2;
        const int Ksrc  = (l == 0) ? EQ  : HQ;
        conv_split<<<(Ncols * (Kp / 2) + 255) / 256, 256, 0, stream>>>(Wl[l], Whi, Wlo, Ncols, Ksrc, Kp);
        const uint16_t* Ah = (l == 0) ? A1hi : Xhi;
        const uint16_t* Al = (l == 0) ? A1lo : Xlo;
        const int ncb = (Ncols + 255) / 256;
        const int cpg = (ncb + 7) / 8;                 // col-groups per XCD
        dim3 gg(8 * cpg * nrb);
        for (int s0 = 0; s0 < SQ; s0 += Sc) {
            if (l == 0)
                gemm256<KP1><<<gg, 512, 131072, stream>>>(Ah, Al, Whi, Wlo, Yc, Ncols, s0 * BQ, nrb, ncb);
            else
                gemm256<KP2><<<gg, 512, 131072, stream>>>(Ah, Al, Whi, Wlo, Yc, Ncols, s0 * BQ, nrb, ncb);
            if (l == 0)
                scan_k<0><<<sgrid, 256, 0, stream>>>(Yc, bl[0], Xhi, Xlo, cst, fin, nullptr, nullptr, s0, Sc);
            else if (l == 1)
                scan_k<1><<<sgrid, 256, 0, stream>>>(Yc, bl[1], Xhi, Xlo, cst, fin, nullptr, nullptr, s0, Sc);
            else
                scan_k<2><<<sgrid, 256, 0, stream>>>(Yc, bl[2], nullptr, nullptr, cst, fin, out, slen, s0, Sc);
        }
    }
}

// Round 6
// 2184.027 us; speedup vs baseline: 1.2042x; 1.0070x over previous
//
#include <hip/hip_runtime.h>
#include <math.h>
#include <stdint.h>
#include <stddef.h>

#define AS1 __attribute__((address_space(1)))
#define AS3 __attribute__((address_space(3)))

typedef __attribute__((ext_vector_type(8))) __bf16 bf16x8;
typedef __attribute__((ext_vector_type(4))) float f32x4;

// Problem constants
#define SQ   256
#define BQ   32
#define EQ   300
#define HQ   2400
#define MQ   (SQ * BQ)      // 8192 rows
#define N3H  7200           // 3 gates
#define N2H  4800           // Z,F only (layer 3)
#define KP1  320            // padded E  (mult of 64)
#define KP2  2432           // padded H  (mult of 64)

// ---------- helpers ----------
__device__ __forceinline__ uint16_t f2bf(float x) {
    uint32_t u = __float_as_uint(x);
    u += 0x7FFFu + ((u >> 16) & 1u);
    return (uint16_t)(u >> 16);
}
__device__ __forceinline__ float bf2f(uint16_t b) {
    return __uint_as_float(((uint32_t)b) << 16);
}
__device__ __forceinline__ float sigm(float x) { return 1.f / (1.f + __expf(-x)); }
__device__ __forceinline__ float tanh_f(float x) { return 2.f / (1.f + __expf(-2.f * x)) - 1.f; }

// ---------- fp32 -> (bf16 hi, bf16 lo) with zero K-padding (pairwise) ----------
__global__ void conv_split(const float* __restrict__ src, uint16_t* __restrict__ hi,
                           uint16_t* __restrict__ lo, int rows, int K, int Kp) {
    int idx = blockIdx.x * 256 + threadIdx.x;     // pair index
    int kp2 = Kp >> 1;
    if (idx >= rows * kp2) return;
    int r = idx / kp2;
    int k = (idx - r * kp2) << 1;
    float2 v = make_float2(0.f, 0.f);
    if (k < K) v = *(const float2*)(src + (size_t)r * K + k);
    uint16_t h0 = f2bf(v.x), h1 = f2bf(v.y);
    uint32_t hw = (uint32_t)h0 | ((uint32_t)h1 << 16);
    uint32_t lw = (uint32_t)f2bf(v.x - bf2f(h0)) | ((uint32_t)f2bf(v.y - bf2f(h1)) << 16);
    size_t o = (size_t)r * Kp + k;
    *(uint32_t*)(hi + o) = hw;
    *(uint32_t*)(lo + o) = lw;
}

// zero the pad columns [HQ, KP2) of the X (hidden) split buffers, once per call
__global__ void zero_pad_X(uint16_t* __restrict__ hi, uint16_t* __restrict__ lo) {
    int idx = blockIdx.x * 256 + threadIdx.x;
    if (idx >= MQ * ((KP2 - HQ) >> 1)) return;
    int r = idx >> 4;                 // 16 pad pairs
    int c = (idx & 15) << 1;
    size_t off = (size_t)r * KP2 + HQ + c;
    *(uint32_t*)(hi + off) = 0u;
    *(uint32_t*)(lo + off) = 0u;
}

// ---------- fused-segment split GEMM, 256x256 tile, 8 waves, 6-phase K-step ----------
// Per K-step (32 wide): stage Ahi/Alo/Whi/Wlo slabs (64 KiB, double-buffered),
// compute acc += Ahi*Whi + Ahi*Wlo + Alo*Whi as 6 phases x 16 MFMA, each phase
// {4-8 ds_read_b128; s_barrier; setprio(1); 16 MFMA; setprio(0)} (m201-style fine
// interleave). Counted vmcnt(8) at step top only; phase barriers are schedule-only.
// LDS swizzle (conflict-free, verified R4): phys 16B-chunk = log ^ ((row>>1)&3),
// inverse baked into global source addr (linear global_load_lds dest).
// XCD grouping: xcd = blockIdx.x & 7 owns cols == xcd (mod 8), rows fastest.
#define RDA(DST, SAOFF, HALF) do {                                              \
    _Pragma("unroll") for (int t_ = 0; t_ < 4; ++t_)                            \
        DST[t_] = *(const bf16x8*)(sa + (SAOFF) + abase + ((((HALF) << 2) + t_) << 10)); \
} while (0)
#define RDB(DST, SAOFF) do {                                                    \
    _Pragma("unroll") for (int t_ = 0; t_ < 4; ++t_)                            \
        DST[t_] = *(const bf16x8*)(sa + (SAOFF) + bbase + (t_ << 10));          \
} while (0)
#define MM16(A4, B4, MH) do {                                                   \
    __builtin_amdgcn_s_setprio(1);                                              \
    _Pragma("unroll") for (int i_ = 0; i_ < 4; ++i_)                            \
    _Pragma("unroll") for (int j_ = 0; j_ < 4; ++j_)                            \
        acc[((MH) << 2) + i_][j_] = __builtin_amdgcn_mfma_f32_16x16x32_bf16(    \
            A4[i_], B4[j_], acc[((MH) << 2) + i_][j_], 0, 0, 0);                \
    __builtin_amdgcn_s_setprio(0);                                              \
} while (0)
#define SBAR() asm volatile("s_barrier" ::: "memory")

template<int KP>
__global__ __launch_bounds__(512, 2) void gemm256(
    const uint16_t* __restrict__ Ahi, const uint16_t* __restrict__ Alo,
    const uint16_t* __restrict__ Whi, const uint16_t* __restrict__ Wlo,
    float* __restrict__ Y, int Ncols, int rowbase, int nrb, int ncb)
{
    constexpr int NK = KP / 32;
    extern __shared__ char smem[];   // 131072 bytes

    const int d   = blockIdx.x;
    const int xcd = d & 7;
    const int rr  = d >> 3;
    const int row = rr % nrb;
    const int col = (rr / nrb) * 8 + xcd;
    if (col >= ncb) return;
    const int lrow0 = row << 8;          // chunk-local row base
    const int col0  = col << 8;
    const int arow0 = rowbase + lrow0;   // absolute A row base

    const int tid  = threadIdx.x;
    const int lane = tid & 63;
    const int wave = tid >> 6;
    const int wm   = wave >> 2;          // 0..1
    const int wn   = wave & 3;           // 0..3

    // ---- staging constants ----
    const int tq   = tid >> 2;                         // row 0..127 (half-tile)
    const int kc   = tid & 3;                          // dest 16B chunk
    const int kswz = ((kc ^ ((tq >> 1) & 3)) << 3);    // pre-swizzled src k-element
    const size_t aof0 = (size_t)(arow0 + tq) * KP + kswz;
    const size_t aof1 = aof0 + (size_t)128 * KP;
    const int w0 = min(col0 + tq, Ncols - 1);
    const int w1 = min(col0 + 128 + tq, Ncols - 1);
    const size_t bof0 = (size_t)w0 * KP + kswz;
    const size_t bof1 = (size_t)w1 * KP + kswz;
    const int ldst = tid << 4;                         // linear LDS dest byte

    // ---- compute constants ----
    const int fr    = lane & 15;
    const int q     = lane >> 4;
    const int cphys = ((q ^ ((fr >> 1) & 3)) << 4);    // swizzled read byte col
    const int abase = (((wm << 7) + fr) << 6) + cphys; // byte within a 16 KiB region
    const int bbase = (((wn << 6) + fr) << 6) + cphys;

    f32x4 acc[8][4];
    {
        f32x4 z = {0.f, 0.f, 0.f, 0.f};
#pragma unroll
        for (int mb = 0; mb < 8; ++mb)
#pragma unroll
            for (int nb = 0; nb < 4; ++nb) acc[mb][nb] = z;
    }

    auto stage = [&](int slot, int k0) {
        char* dst = smem + (slot << 16);
        __builtin_amdgcn_global_load_lds((const AS1 uint32_t*)(Ahi + aof0 + k0),
                                         (AS3 uint32_t*)(dst + ldst),                 16, 0, 0);
        __builtin_amdgcn_global_load_lds((const AS1 uint32_t*)(Ahi + aof1 + k0),
                                         (AS3 uint32_t*)(dst + 8192  + ldst),         16, 0, 0);
        __builtin_amdgcn_global_load_lds((const AS1 uint32_t*)(Alo + aof0 + k0),
                                         (AS3 uint32_t*)(dst + 16384 + ldst),         16, 0, 0);
        __builtin_amdgcn_global_load_lds((const AS1 uint32_t*)(Alo + aof1 + k0),
                                         (AS3 uint32_t*)(dst + 16384 + 8192 + ldst),  16, 0, 0);
        __builtin_amdgcn_global_load_lds((const AS1 uint32_t*)(Whi + bof0 + k0),
                                         (AS3 uint32_t*)(dst + 32768 + ldst),         16, 0, 0);
        __builtin_amdgcn_global_load_lds((const AS1 uint32_t*)(Whi + bof1 + k0),
                                         (AS3 uint32_t*)(dst + 32768 + 8192 + ldst),  16, 0, 0);
        __builtin_amdgcn_global_load_lds((const AS1 uint32_t*)(Wlo + bof0 + k0),
                                         (AS3 uint32_t*)(dst + 49152 + ldst),         16, 0, 0);
        __builtin_amdgcn_global_load_lds((const AS1 uint32_t*)(Wlo + bof1 + k0),
                                         (AS3 uint32_t*)(dst + 49152 + 8192 + ldst),  16, 0, 0);
    };

    stage(0, 0);
    for (int j = 0; j < NK; ++j) {
        if (j + 1 < NK) {
            stage((j + 1) & 1, (j + 1) << 5);
            asm volatile("s_waitcnt vmcnt(8)" ::: "memory");   // slab j landed (mine)
        } else {
            asm volatile("s_waitcnt vmcnt(0)" ::: "memory");
        }
        SBAR();                                                // slab j landed (all waves)

        const char* sa = smem + ((j & 1) << 16);
        bf16x8 ahi0[4], ahi1[4], alo0[4], alo1[4], bh[4], bl[4];

        // Ph1: read Ahi[0-3] + Whi; MFMA Ahi03 x Whi
        RDA(ahi0, 0, 0); RDB(bh, 32768);
        SBAR(); MM16(ahi0, bh, 0);
        // Ph2: read Ahi[4-7]; MFMA Ahi47 x Whi
        RDA(ahi1, 0, 1);
        SBAR(); MM16(ahi1, bh, 1);
        // Ph3: read Wlo; MFMA Ahi03 x Wlo
        RDB(bl, 49152);
        SBAR(); MM16(ahi0, bl, 0);
        // Ph4: read Alo[0-3]; MFMA Ahi47 x Wlo
        RDA(alo0, 16384, 0);
        SBAR(); MM16(ahi1, bl, 1);
        // Ph5: read Alo[4-7]; MFMA Alo03 x Whi
        RDA(alo1, 16384, 1);
        SBAR(); MM16(alo0, bh, 0);
        // Ph6: MFMA Alo47 x Whi
        MM16(alo1, bh, 1);

        SBAR();   // step end: all reads of slot j done before it is restaged
    }

    // epilogue: D col = lane&15, row = (lane>>4)*4 + r   (chunk-local Y rows)
    const int orow = (lane >> 4) << 2;
    const int ocol = lane & 15;
#pragma unroll
    for (int mb = 0; mb < 8; ++mb) {
        const int r0 = lrow0 + (wm << 7) + (mb << 4) + orow;
#pragma unroll
        for (int nb = 0; nb < 4; ++nb) {
            const int c = col0 + (wn << 6) + (nb << 4) + ocol;
            if (c < Ncols) {
                float* yp = Y + (size_t)r0 * Ncols + c;
#pragma unroll
                for (int r = 0; r < 4; ++r) yp[(size_t)r * Ncols] = acc[mb][nb][r];
            }
        }
    }
}

// ---------- fo-pool scan chunk [s0, s0+Sc); 2 h-columns per thread ----------
// MODE 0: layer1 (finals=c), MODE 1: layer2 (finals+=c), MODE 2: layer3 (Z,F only; output)
template<int MODE>
__global__ void scan_k(const float* __restrict__ Y, const float* __restrict__ bias,
                       uint16_t* __restrict__ hhi, uint16_t* __restrict__ hlo,
                       float* __restrict__ cst, float* __restrict__ fin,
                       float* __restrict__ out, const int* __restrict__ slen,
                       int s0, int Sc)
{
    int idx = blockIdx.x * 256 + threadIdx.x;     // pair index
    if (idx >= BQ * (HQ >> 1)) return;
    int b = idx / (HQ >> 1);
    int h = (idx - b * (HQ >> 1)) << 1;
    const int Ncols = (MODE == 2) ? N2H : N3H;

    const float2 bz = *(const float2*)(bias + h);
    const float2 bg = *(const float2*)(bias + HQ + h);
    const float2 bo = (MODE == 2) ? make_float2(0.f, 0.f) : *(const float2*)(bias + 2 * HQ + h);
    float2 c = (s0 == 0) ? make_float2(0.f, 0.f) : *(const float2*)(cst + b * HQ + h);

    const float* yp = Y + (size_t)b * Ncols + h;
    for (int si = 0; si < Sc; ++si) {
        const float* row = yp + (size_t)si * (BQ * Ncols);
        float2 zr = *(const float2*)(row);
        float2 fr = *(const float2*)(row + HQ);
        float z0 = tanh_f(zr.x + bz.x), z1 = tanh_f(zr.y + bz.y);
        float f0 = sigm(fr.x + bg.x),   f1 = sigm(fr.y + bg.y);
        c.x = f0 * c.x + (1.f - f0) * z0;
        c.y = f1 * c.y + (1.f - f1) * z1;
        if (MODE != 2) {
            float2 orv = *(const float2*)(row + 2 * HQ);
            float o0 = sigm(orv.x + bo.x), o1 = sigm(orv.y + bo.y);
            float h0 = o0 * c.x, h1 = o1 * c.y;
            uint16_t hb0 = f2bf(h0), hb1 = f2bf(h1);
            size_t off = ((size_t)(s0 + si) * BQ + b) * KP2 + h;
            *(uint32_t*)(hhi + off) = (uint32_t)hb0 | ((uint32_t)hb1 << 16);
            *(uint32_t*)(hlo + off) =
                (uint32_t)f2bf(h0 - bf2f(hb0)) | ((uint32_t)f2bf(h1 - bf2f(hb1)) << 16);
        }
    }
    if (s0 + Sc < SQ) {
        *(float2*)(cst + b * HQ + h) = c;
    } else {
        if (MODE == 0) {
            *(float2*)(fin + b * HQ + h) = c;
        } else if (MODE == 1) {
            float2 t = *(const float2*)(fin + b * HQ + h);
            t.x += c.x; t.y += c.y;
            *(float2*)(fin + b * HQ + h) = t;
        } else {
            float inv = 1.f / (float)slen[b];
            float2 t = *(const float2*)(fin + b * HQ + h);
            out[b * HQ + h]     = (t.x + c.x) * inv;
            out[b * HQ + h + 1] = (t.y + c.y) * inv;
        }
    }
}

extern "C" void kernel_launch(void* const* d_in, const int* in_sizes, int n_in,
                              void* d_out, int out_size, void* d_ws, size_t ws_size,
                              hipStream_t stream) {
    const float* sent = (const float*)d_in[0];
    const int*   slen = (const int*)d_in[1];
    const float* Wl[3] = {(const float*)d_in[2], (const float*)d_in[4], (const float*)d_in[6]};
    const float* bl[3] = {(const float*)d_in[3], (const float*)d_in[5], (const float*)d_in[7]};
    float* out = (float*)d_out;

    // allow 128 KiB dynamic LDS for the GEMM kernels (host-side, capture-safe)
    (void)hipFuncSetAttribute((const void*)gemm256<KP1>,
                              hipFuncAttributeMaxDynamicSharedMemorySize, 131072);
    (void)hipFuncSetAttribute((const void*)gemm256<KP2>,
                              hipFuncAttributeMaxDynamicSharedMemorySize, 131072);

    // ws layout (fixed part ~153.4 MiB; Y chunk sized to fit ws_size)
    char* ws = (char*)d_ws;
    uint16_t* A1hi = (uint16_t*)ws;                    // [8192][320]
    uint16_t* A1lo = A1hi + (size_t)MQ * KP1;
    uint16_t* Xhi  = A1lo + (size_t)MQ * KP1;          // [8192][2432]
    uint16_t* Xlo  = Xhi  + (size_t)MQ * KP2;
    uint16_t* Whi  = Xlo  + (size_t)MQ * KP2;          // [7200][2432] max
    uint16_t* Wlo  = Whi  + (size_t)N3H * KP2;
    float*    cst  = (float*)(Wlo + (size_t)N3H * KP2);// [32][2400]
    float*    fin  = cst + (size_t)BQ * HQ;            // [32][2400]
    float*    Yc   = fin + (size_t)BQ * HQ;            // [Sc*32][7200] fp32

    const size_t fixed = (size_t)((char*)Yc - ws);
    int Sc = 8;
    const int sc_opts[6] = {256, 128, 64, 32, 16, 8};  // multiples of 8 (M-tile = 256 rows)
    for (int i = 0; i < 6; ++i) {
        size_t need = fixed + (size_t)sc_opts[i] * BQ * N3H * 4 + 256;
        if (need <= ws_size) { Sc = sc_opts[i]; break; }
    }
    const int nrb = Sc / 8;   // 256-row tiles per chunk

    conv_split<<<(MQ * (KP1 / 2) + 255) / 256, 256, 0, stream>>>(sent, A1hi, A1lo, MQ, EQ, KP1);
    zero_pad_X<<<(MQ * 16 + 255) / 256, 256, 0, stream>>>(Xhi, Xlo);

    const int sgrid = (BQ * (HQ / 2) + 255) / 256;
    for (int l = 0; l < 3; ++l) {
        const int Ncols = (l == 2) ? N2H : N3H;
        const int Kp    = (l == 0) ? KP1 : KP2;
        const int Ksrc  = (l == 0) ? EQ  : HQ;
        conv_split<<<(Ncols * (Kp / 2) + 255) / 256, 256, 0, stream>>>(Wl[l], Whi, Wlo, Ncols, Ksrc, Kp);
        const uint16_t* Ah = (l == 0) ? A1hi : Xhi;
        const uint16_t* Al = (l == 0) ? A1lo : Xlo;
        const int ncb = (Ncols + 255) / 256;
        const int cpg = (ncb + 7) / 8;                 // col-groups per XCD
        dim3 gg(8 * cpg * nrb);
        for (int s0 = 0; s0 < SQ; s0 += Sc) {
            if (l == 0)
                gemm256<KP1><<<gg, 512, 131072, stream>>>(Ah, Al, Whi, Wlo, Yc, Ncols, s0 * BQ, nrb, ncb);
            else
                gemm256<KP2><<<gg, 512, 131072, stream>>>(Ah, Al, Whi, Wlo, Yc, Ncols, s0 * BQ, nrb, ncb);
            if (l == 0)
                scan_k<0><<<sgrid, 256, 0, stream>>>(Yc, bl[0], Xhi, Xlo, cst, fin, nullptr, nullptr, s0, Sc);
            else if (l == 1)
                scan_k<1><<<sgrid, 256, 0, stream>>>(Yc, bl[1], Xhi, Xlo, cst, fin, nullptr, nullptr, s0, Sc);
            else
                scan_k<2><<<sgrid, 256, 0, stream>>>(Yc, bl[2], nullptr, nullptr, cst, fin, out, slen, s0, Sc);
        }
    }
}